// Round 20
// baseline (801.726 us; speedup 1.0000x reference)
//
#include <hip/hip_runtime.h>

// Seq2SeqDecoder: 2-layer GRU (reset_after) + logit projection, MI355X/gfx950.
// B=32 T=64 V=32000 E=512 H=1024.
// R20 = R19 (weights-in-LDS chain: coop 680us, total 789us) +
//   (a) ALL-WAVE flag polling, post-poll __syncthreads removed (each wave
//       proceeds on its own detection; red-buffer hazard still fenced by the
//       two later barriers in the loop body)
//   (b) k_embed+k_init fused into one launch; helper band-wait sleep 32->8.
//   phase 0: k_tconv4 (fused small transposes) + k_tconv(Wd); k_prep
//   phase 1: MX0 = xin @ k0t + b0[0]        (dist-2 pipelined bf16 MFMA GEMM)
//   phase 2: ONE cooperative kernel, 256 blocks:
//     blocks 0..191: recurrence, weights in LDS (96KB/block, staged once,
//       ds_read_b128 for all 66 steps -- R19's +231us lever)
//     blocks 192..255 (+ finished chain blocks): work-stealing logits GEMM
//       (dist-2, 7.6us/tile), seq1 t-major, band r ready at FL2[*] >= 4r+6
//   phase 3: final states -> d_out tail

typedef __attribute__((ext_vector_type(8))) short bf16x8;
typedef __attribute__((ext_vector_type(4))) float f32x4;
typedef unsigned short u16;
typedef unsigned int u32;

#define CHAIN_BLOCKS 192
#define TOTAL_BLOCKS 256
#define NTILE 4000u              // 16 row-bands x 250 col-tiles
#define BAR_WORDS 3136           // FL0/FL1/FL2 (3x64 flags, 64B spaced) + wcnt

__device__ __forceinline__ u16 f2bf(float f) {
  unsigned int x = __float_as_uint(f);
  x += 0x7fffu + ((x >> 16) & 1u);   // RNE
  return (u16)(x >> 16);
}

// sc1 write-through stores (visible at L3 after vmcnt drain)
__device__ __forceinline__ void astoref(float* p, float v) {
  __hip_atomic_store((u32*)p, __float_as_uint(v), __ATOMIC_RELAXED,
                     __HIP_MEMORY_SCOPE_AGENT);
}
__device__ __forceinline__ void astore32(u16* p, u32 v) {
  __hip_atomic_store((u32*)p, v, __ATOMIC_RELAXED, __HIP_MEMORY_SCOPE_AGENT);
}

// ---- transpose + convert: in f32 [R][C] -> out bf16 [C][R] ----------------
__global__ void k_tconv(const float* __restrict__ in, u16* __restrict__ out,
                        int R, int C) {
  __shared__ float t[32][33];
  int tx = threadIdx.x, ty = threadIdx.y;          // 32 x 8
  int c0 = blockIdx.x * 32, r0 = blockIdx.y * 32;
#pragma unroll
  for (int i = 0; i < 4; ++i)
    t[ty + i * 8][tx] = in[(long)(r0 + ty + i * 8) * C + c0 + tx];
  __syncthreads();
#pragma unroll
  for (int i = 0; i < 4; ++i)
    out[(long)(c0 + ty + i * 8) * R + r0 + tx] = f2bf(t[tx][ty + i * 8]);
}

// ---- fused transpose of the four small weights (one launch) ---------------
__global__ void k_tconv4(const float* __restrict__ k0,
                         const float* __restrict__ rk0,
                         const float* __restrict__ k1,
                         const float* __restrict__ rk1,
                         u16* __restrict__ k0t, u16* __restrict__ rk0t,
                         u16* __restrict__ k1t, u16* __restrict__ rk1t) {
  __shared__ float t[32][33];
  int blk = blockIdx.x;
  const float* in; u16* out; int R;
  if (blk < 4608) {
    in = k0; out = k0t; R = 1536;
  } else {
    int q = (blk - 4608) / 3072;
    blk = (blk - 4608) % 3072;
    in = (q == 0) ? rk0 : (q == 1) ? k1 : rk1;
    out = (q == 0) ? rk0t : (q == 1) ? k1t : rk1t;
    R = 1024;
  }
  const int bx = blk % 96, by = blk / 96;
  const int tx = threadIdx.x, ty = threadIdx.y;    // 32 x 8
  const int c0 = bx * 32, r0 = by * 32;
#pragma unroll
  for (int i = 0; i < 4; ++i)
    t[ty + i * 8][tx] = in[(long)(r0 + ty + i * 8) * 3072 + c0 + tx];
  __syncthreads();
#pragma unroll
  for (int i = 0; i < 4; ++i)
    out[(long)(c0 + ty + i * 8) * R + r0 + tx] = f2bf(t[tx][ty + i * 8]);
}

// ---- fused embed + init (one launch) --------------------------------------
// blocks [0,2048): xin build; blocks [2048,2176): state/flag init
__global__ void k_prep(const int* __restrict__ X, const float* __restrict__ state,
                       const float* __restrict__ emb, u16* __restrict__ xin,
                       u16* __restrict__ H0, u16* __restrict__ H1,
                       float* __restrict__ h0f, float* __restrict__ h1f,
                       u32* __restrict__ bar) {
  const int blk = blockIdx.x;
  if (blk < 2048) {
    const int bt = blk;
    const int b = bt >> 6;
    const int tok = X[bt];
    const float* er = emb + (long)tok * 512;
    const float* cr = state + 32 * 1024 + b * 1024;  // state[-1] == state[1]
    for (int c = threadIdx.x; c < 1536; c += 256) {
      float v = (c < 512) ? er[c] : cr[c - 512];
      xin[(long)bt * 1536 + c] = f2bf(v);
    }
  } else {
    const int i = (blk - 2048) * 256 + threadIdx.x;  // 128 blocks -> 32768
    if (i < BAR_WORDS) bar[i] = 0u;
    float v0 = state[i], v1 = state[32768 + i];
    H0[i] = f2bf(v0);             // slot 0 = h0(-1)
    h0f[32768 + i] = v0;          // parity 1
    H1[i] = f2bf(v1);             // slot 0 = h1(-1)
    h1f[32768 + i] = v1;
  }
}

// ---- bf16 GEMM (MX0): dist-2 pipelined, K multiple of 64 ------------------
__global__ void k_gemm(const u16* __restrict__ A, const u16* __restrict__ Bt,
                       const float* __restrict__ bias, float* __restrict__ C,
                       int M, int N, int K) {
  __shared__ u16 As[128][40];
  __shared__ u16 Bs[128][40];
  int tid = threadIdx.x;
  int w = tid >> 6, l = tid & 63;
  int ln = l & 15, lk = l >> 4;
  int r0 = blockIdx.x * 128, c0 = blockIdx.y * 128;
  int qr = (w & 1) * 64, qc = (w >> 1) * 64;
  int sr = tid >> 1, sc = (tid & 1) * 16;
  const u16* Ap = A + (long)(r0 + sr) * K + sc;
  const u16* Bp = Bt + (long)(c0 + sr) * K + sc;
  f32x4 acc[4][4] = {};
  bf16x8 a0A = *(const bf16x8*)(Ap);
  bf16x8 a1A = *(const bf16x8*)(Ap + 8);
  bf16x8 b0A = *(const bf16x8*)(Bp);
  bf16x8 b1A = *(const bf16x8*)(Bp + 8);
  bf16x8 a0B = *(const bf16x8*)(Ap + 32);
  bf16x8 a1B = *(const bf16x8*)(Ap + 40);
  bf16x8 b0B = *(const bf16x8*)(Bp + 32);
  bf16x8 b1B = *(const bf16x8*)(Bp + 40);
  for (int kt = 0; kt < K; kt += 64) {
    __syncthreads();
    *(bf16x8*)(&As[sr][sc]) = a0A;  *(bf16x8*)(&As[sr][sc + 8]) = a1A;
    *(bf16x8*)(&Bs[sr][sc]) = b0A;  *(bf16x8*)(&Bs[sr][sc + 8]) = b1A;
    __syncthreads();
    if (kt + 64 < K) {
      a0A = *(const bf16x8*)(Ap + kt + 64);
      a1A = *(const bf16x8*)(Ap + kt + 72);
      b0A = *(const bf16x8*)(Bp + kt + 64);
      b1A = *(const bf16x8*)(Bp + kt + 72);
    }
    {
      bf16x8 af[4], bfv[4];
#pragma unroll
      for (int mt = 0; mt < 4; ++mt)
        af[mt] = *(const bf16x8*)(&As[qr + mt * 16 + ln][lk * 8]);
#pragma unroll
      for (int nt = 0; nt < 4; ++nt)
        bfv[nt] = *(const bf16x8*)(&Bs[qc + nt * 16 + ln][lk * 8]);
#pragma unroll
      for (int mt = 0; mt < 4; ++mt)
#pragma unroll
        for (int nt = 0; nt < 4; ++nt)
          acc[mt][nt] = __builtin_amdgcn_mfma_f32_16x16x32_bf16(
              af[mt], bfv[nt], acc[mt][nt], 0, 0, 0);
    }
    __syncthreads();
    *(bf16x8*)(&As[sr][sc]) = a0B;  *(bf16x8*)(&As[sr][sc + 8]) = a1B;
    *(bf16x8*)(&Bs[sr][sc]) = b0B;  *(bf16x8*)(&Bs[sr][sc + 8]) = b1B;
    __syncthreads();
    if (kt + 96 < K) {
      a0B = *(const bf16x8*)(Ap + kt + 96);
      a1B = *(const bf16x8*)(Ap + kt + 104);
      b0B = *(const bf16x8*)(Bp + kt + 96);
      b1B = *(const bf16x8*)(Bp + kt + 104);
    }
    {
      bf16x8 af[4], bfv[4];
#pragma unroll
      for (int mt = 0; mt < 4; ++mt)
        af[mt] = *(const bf16x8*)(&As[qr + mt * 16 + ln][lk * 8]);
#pragma unroll
      for (int nt = 0; nt < 4; ++nt)
        bfv[nt] = *(const bf16x8*)(&Bs[qc + nt * 16 + ln][lk * 8]);
#pragma unroll
      for (int mt = 0; mt < 4; ++mt)
#pragma unroll
        for (int nt = 0; nt < 4; ++nt)
          acc[mt][nt] = __builtin_amdgcn_mfma_f32_16x16x32_bf16(
              af[mt], bfv[nt], acc[mt][nt], 0, 0, 0);
    }
  }
#pragma unroll
  for (int mt = 0; mt < 4; ++mt)
#pragma unroll
    for (int nt = 0; nt < 4; ++nt)
#pragma unroll
      for (int r = 0; r < 4; ++r) {
        int row = r0 + qr + mt * 16 + lk * 4 + r;
        int col = c0 + qc + nt * 16 + ln;
        __builtin_nontemporal_store(acc[mt][nt][r] + bias[col],
                                    &C[(long)row * N + col]);
      }
}

// ---- cooperative: recurrence (weights in LDS) + fused logits GEMM ---------
__global__ void __launch_bounds__(256, 1)
k_chain(const u16* __restrict__ rk0t, const u16* __restrict__ k1t,
        const u16* __restrict__ rk1t, const float* __restrict__ MX0,
        const float* __restrict__ b0, const float* __restrict__ b1,
        float* __restrict__ MX1, u16* __restrict__ H0, u16* __restrict__ H1,
        float* __restrict__ h0f, float* __restrict__ h1f,
        u16* __restrict__ seq1, u32* __restrict__ bar,
        const u16* __restrict__ Wdt, const float* __restrict__ bd,
        float* __restrict__ out) {
  // 105,472 B carve: chain phase = wS(98304) + red(6144) + hbS(1024);
  // GEMM phase reuses [0,20480) as As/Bs.
  __shared__ __align__(16) char smem[105472];
  __shared__ u32 tauS;
  u16* wS = (u16*)smem;
  float (*red)[3][4][64] = (float(*)[3][4][64])(smem + 98304);
  u16 (*hbS)[16] = (u16(*)[16])(smem + 98304 + 6144);
  u16 (*As)[40] = (u16(*)[40])(smem);
  u16 (*Bs)[40] = (u16(*)[40])(smem + 10240);

  const int blk = blockIdx.x;
  const int type = blk >> 6;          // 0:L0  1:MX1  2:L1  3:helper
  const int cb = blk & 63;
  const int j0 = cb << 4;             // 16 h-cols per block
  const int tid = threadIdx.x;
  const int w = tid >> 6, l = tid & 63;
  const int ln = l & 15, lk = l >> 4;
  const int rt = w & 1, kh = w >> 1;  // row-tile (16 rows), K-half (512)

  // entry acquire: buffer_inv drops pre-launch L2 lines (per-t buffers fresh)
  if (tid == 0)
    (void)__hip_atomic_load(bar, __ATOMIC_ACQUIRE, __HIP_MEMORY_SCOPE_AGENT);
  __syncthreads();

  if (blk < CHAIN_BLOCKS) {
    // ================== R10-structure recurrence ==================
    const u16* Wt = (type == 0) ? rk0t : (type == 1) ? k1t : rk1t;
    u32* myflag = bar + type * 1024 + cb * 16;

    // ---- stage this block's 3x16x1024 weight slice into LDS (once) ----
    // layout: [gate][q=k/8][col][8] (16B units); 2-way bank aliasing = free.
    for (int idx = tid; idx < 6144; idx += 256) {
      const int g = idx >> 11;
      const int rem = idx & 2047;
      const int c = rem >> 7;             // col 0..15
      const int q = rem & 127;            // k-chunk 0..127
      *(bf16x8*)(wS + g * 16384 + (((q << 4) + c) << 3)) =
          *(const bf16x8*)(Wt + ((long)g << 20) + (long)(j0 + c) * 1024 +
                           (q << 3));
    }
    __syncthreads();
    const u16* wls = wS + ((((kh << 6) + lk) << 4) + ln) * 8;

    for (int s = 0; s < 66; ++s) {
      const int tt = (type == 0) ? s : (type == 1) ? s - 1 : s - 2;
      const bool active = (tt >= 0) && (tt < 64);

      // MX0 prefetch (static data, issued BEFORE the poll)
      float pf[4][3];
      if (type == 0 && kh == 0 && active) {
        const int j = j0 + ln;
#pragma unroll
        for (int r = 0; r < 4; ++r) {
          const float* mx = MX0 + (((long)(rt * 16 + lk * 4 + r)) * 64 + tt) * 3072;
          pf[r][0] = mx[j]; pf[r][1] = mx[1024 + j]; pf[r][2] = mx[2048 + j];
        }
      }

      // dependency poll: ALL waves scan the flags (lane l = flag index);
      // no post-poll barrier -- each wave proceeds on its own detection.
      // red(s+1)-write vs red(s)-read hazard is fenced by the two later
      // __syncthreads in this loop body.
      {
        const u32 tgt = (u32)s;
        if (type != 2) {
          const u32* f = bar + l * 16;                         // FL0
          while (true) {
            u32 v = __hip_atomic_load(f, __ATOMIC_RELAXED,
                                      __HIP_MEMORY_SCOPE_AGENT);
            if (__all(v >= tgt)) break;
            __builtin_amdgcn_s_sleep(1);
          }
        } else {
          const u32* fa = bar + 1024 + l * 16;                 // FL1
          const u32* fb = bar + 2048 + l * 16;                 // FL2
          while (true) {
            u32 va = __hip_atomic_load(fa, __ATOMIC_RELAXED,
                                       __HIP_MEMORY_SCOPE_AGENT);
            u32 vb = __hip_atomic_load(fb, __ATOMIC_RELAXED,
                                       __HIP_MEMORY_SCOPE_AGENT);
            if (__all(va >= tgt && vb >= tgt)) break;
            __builtin_amdgcn_s_sleep(1);
          }
        }
      }

      f32x4 acc[3] = {};
      if (active) {
        if (type == 2 && kh == 0) {
          const int j = j0 + ln;
#pragma unroll
          for (int r = 0; r < 4; ++r) {
            const float* mx = MX1 + (long)tt * 98304 +
                              (long)(rt * 16 + lk * 4 + r) * 3072;
            pf[r][0] = mx[j]; pf[r][1] = mx[1024 + j]; pf[r][2] = mx[2048 + j];
          }
        }
        const u16* Ab = (type == 2) ? H1 + (long)tt * 32768
                                    : H0 + (long)s * 32768;
        const u16* hp = Ab + (rt * 16 + ln) * 1024 + kh * 512 + lk * 8;
        bf16x8 afr[16];
#pragma unroll
        for (int ks = 0; ks < 16; ++ks)
          afr[ks] = *(const bf16x8*)(hp + ks * 32);
#pragma unroll
        for (int ks = 0; ks < 16; ++ks) {
          bf16x8 bv0 = *(const bf16x8*)(wls + ks * 512);
          bf16x8 bv1 = *(const bf16x8*)(wls + 16384 + ks * 512);
          bf16x8 bv2 = *(const bf16x8*)(wls + 32768 + ks * 512);
          acc[0] = __builtin_amdgcn_mfma_f32_16x16x32_bf16(afr[ks], bv0, acc[0], 0, 0, 0);
          acc[1] = __builtin_amdgcn_mfma_f32_16x16x32_bf16(afr[ks], bv1, acc[1], 0, 0, 0);
          acc[2] = __builtin_amdgcn_mfma_f32_16x16x32_bf16(afr[ks], bv2, acc[2], 0, 0, 0);
        }
        if (kh == 1) {
#pragma unroll
          for (int g = 0; g < 3; ++g)
#pragma unroll
            for (int r = 0; r < 4; ++r)
              red[rt][g][r][l] = acc[g][r];
        }
      }
      __syncthreads();
      if (active && kh == 0) {
#pragma unroll
        for (int r = 0; r < 4; ++r) {
          const int row = rt * 16 + lk * 4 + r;    // batch b
          const int j = j0 + ln;
          float mz = acc[0][r] + red[rt][0][r][l];
          float mr = acc[1][r] + red[rt][1][r][l];
          float mh = acc[2][r] + red[rt][2][r][l];
          if (type == 1) {
            float* o = MX1 + (long)tt * 98304 + (long)row * 3072;
            astoref(o + j,        mz + b1[j]);
            astoref(o + 1024 + j, mr + b1[1024 + j]);
            astoref(o + 2048 + j, mh + b1[2048 + j]);
          } else {
            const float* bias = (type == 0) ? b0 + 3072 : b1 + 3072;  // b[1]
            float miz = mz + bias[j];
            float mir = mr + bias[1024 + j];
            float mih = mh + bias[2048 + j];
            float z  = 1.f / (1.f + expf(-(pf[r][0] + miz)));
            float rg = 1.f / (1.f + expf(-(pf[r][1] + mir)));
            float hh = tanhf(pf[r][2] + rg * mih);
            float* hf = (type == 0) ? h0f : h1f;
            float hold = hf[(long)((tt + 1) & 1) * 32768 + row * 1024 + j];
            float hn = z * hold + (1.f - z) * hh;
            hf[(long)(tt & 1) * 32768 + row * 1024 + j] = hn;
            hbS[row][ln] = f2bf(hn);
          }
        }
      }
      if (type != 1) {
        __syncthreads();
        if (active) {
          const int row = tid >> 3, cp = tid & 7;
          const u32 v = ((const u32*)&hbS[row][0])[cp];
          const int j = j0 + cp * 2;
          if (type == 0) {
            astore32(&H0[(long)(tt + 1) * 32768 + row * 1024 + j], v);
          } else {
            astore32(&H1[(long)(tt + 1) * 32768 + row * 1024 + j], v);
            // seq1 T-MAJOR (row = t*32 + b), sc1 so helper blocks see it
            astore32(&seq1[((long)tt * 32 + row) * 1024 + j], v);
          }
        }
      }
      asm volatile("s_waitcnt vmcnt(0)" ::: "memory");
      __syncthreads();
      if (tid == 0)
        __hip_atomic_store(myflag, (u32)(s + 1), __ATOMIC_RELAXED,
                           __HIP_MEMORY_SCOPE_AGENT);
    }
  }

  // ================== fused logits GEMM (all blocks) ==================
  // out[b*64+t][v] = seq1_tmajor[t*32+b][:] @ Wdt[v][:] + bd[v]
  u32* wcnt = bar + 3072;
  const int qr = (w & 1) * 64, qc = (w >> 1) * 64;
  const int sr = tid >> 1, sc = (tid & 1) * 16;
  u32 seen = 0;
  for (;;) {
    if (tid == 0) tauS = atomicAdd(wcnt, 1u);
    __syncthreads();
    const u32 tau = tauS;
    __syncthreads();
    if (tau >= NTILE) break;
    const u32 rr = tau / 250u, cc = tau % 250u;
    u32 need = 4u * rr + 6u; if (need > 66u) need = 66u;
    if (seen < need) {
      if (tid < 64) {
        const u32* f = bar + 2048 + tid * 16;                  // FL2
        while (true) {
          u32 v = __hip_atomic_load(f, __ATOMIC_RELAXED,
                                    __HIP_MEMORY_SCOPE_AGENT);
          if (__all(v >= need)) break;
          __builtin_amdgcn_s_sleep(8);
        }
      }
      __syncthreads();
      seen = need;
    }
    const int r0g = (int)rr * 128, c0g = (int)cc * 128;
    const u16* Ap = seq1 + (long)(r0g + sr) * 1024 + sc;
    const u16* Bp = Wdt + (long)(c0g + sr) * 1024 + sc;
    f32x4 accg[4][4] = {};
    bf16x8 a0A = *(const bf16x8*)(Ap);
    bf16x8 a1A = *(const bf16x8*)(Ap + 8);
    bf16x8 b0A = *(const bf16x8*)(Bp);
    bf16x8 b1A = *(const bf16x8*)(Bp + 8);
    bf16x8 a0B = *(const bf16x8*)(Ap + 32);
    bf16x8 a1B = *(const bf16x8*)(Ap + 40);
    bf16x8 b0B = *(const bf16x8*)(Bp + 32);
    bf16x8 b1B = *(const bf16x8*)(Bp + 40);
    for (int kt = 0; kt < 1024; kt += 64) {
      __syncthreads();
      *(bf16x8*)(&As[sr][sc]) = a0A;  *(bf16x8*)(&As[sr][sc + 8]) = a1A;
      *(bf16x8*)(&Bs[sr][sc]) = b0A;  *(bf16x8*)(&Bs[sr][sc + 8]) = b1A;
      __syncthreads();
      if (kt + 64 < 1024) {
        a0A = *(const bf16x8*)(Ap + kt + 64);
        a1A = *(const bf16x8*)(Ap + kt + 72);
        b0A = *(const bf16x8*)(Bp + kt + 64);
        b1A = *(const bf16x8*)(Bp + kt + 72);
      }
      {
        bf16x8 af[4], bfv[4];
#pragma unroll
        for (int mt = 0; mt < 4; ++mt)
          af[mt] = *(const bf16x8*)(&As[qr + mt * 16 + ln][lk * 8]);
#pragma unroll
        for (int nt = 0; nt < 4; ++nt)
          bfv[nt] = *(const bf16x8*)(&Bs[qc + nt * 16 + ln][lk * 8]);
#pragma unroll
        for (int mt = 0; mt < 4; ++mt)
#pragma unroll
          for (int nt = 0; nt < 4; ++nt)
            accg[mt][nt] = __builtin_amdgcn_mfma_f32_16x16x32_bf16(
                af[mt], bfv[nt], accg[mt][nt], 0, 0, 0);
      }
      __syncthreads();
      *(bf16x8*)(&As[sr][sc]) = a0B;  *(bf16x8*)(&As[sr][sc + 8]) = a1B;
      *(bf16x8*)(&Bs[sr][sc]) = b0B;  *(bf16x8*)(&Bs[sr][sc + 8]) = b1B;
      __syncthreads();
      if (kt + 96 < 1024) {
        a0B = *(const bf16x8*)(Ap + kt + 96);
        a1B = *(const bf16x8*)(Ap + kt + 104);
        b0B = *(const bf16x8*)(Bp + kt + 96);
        b1B = *(const bf16x8*)(Bp + kt + 104);
      }
      {
        bf16x8 af[4], bfv[4];
#pragma unroll
        for (int mt = 0; mt < 4; ++mt)
          af[mt] = *(const bf16x8*)(&As[qr + mt * 16 + ln][lk * 8]);
#pragma unroll
        for (int nt = 0; nt < 4; ++nt)
          bfv[nt] = *(const bf16x8*)(&Bs[qc + nt * 16 + ln][lk * 8]);
#pragma unroll
        for (int mt = 0; mt < 4; ++mt)
#pragma unroll
          for (int nt = 0; nt < 4; ++nt)
            accg[mt][nt] = __builtin_amdgcn_mfma_f32_16x16x32_bf16(
                af[mt], bfv[nt], accg[mt][nt], 0, 0, 0);
      }
    }
    __syncthreads();   // LDS safe before next tile's writes
#pragma unroll
    for (int mt = 0; mt < 4; ++mt)
#pragma unroll
      for (int nt = 0; nt < 4; ++nt)
#pragma unroll
        for (int r = 0; r < 4; ++r) {
          const int m = r0g + qr + mt * 16 + lk * 4 + r;       // t*32+b
          const int orow = (m & 31) * 64 + (m >> 5);           // b*64+t
          const int col = c0g + qc + nt * 16 + ln;
          __builtin_nontemporal_store(accg[mt][nt][r] + bd[col],
                                      &out[(long)orow * 32000 + col]);
        }
  }
}

__global__ void k_states(const float* __restrict__ h0, const float* __restrict__ h1,
                         float* __restrict__ out) {
  int i = blockIdx.x * 256 + threadIdx.x;        // grid 128
  out[i] = h0[i];
  out[32768 + i] = h1[i];
}

extern "C" void kernel_launch(void* const* d_in, const int* in_sizes, int n_in,
                              void* d_out, int out_size, void* d_ws, size_t ws_size,
                              hipStream_t stream) {
  const int*   X     = (const int*)  d_in[0];
  const float* state = (const float*)d_in[1];
  const float* emb   = (const float*)d_in[2];
  const float* k0    = (const float*)d_in[3];
  const float* rk0   = (const float*)d_in[4];
  const float* b0    = (const float*)d_in[5];
  const float* k1    = (const float*)d_in[6];
  const float* rk1   = (const float*)d_in[7];
  const float* b1    = (const float*)d_in[8];
  const float* Wd    = (const float*)d_in[9];
  const float* bd    = (const float*)d_in[10];
  float* out = (float*)d_out;

  char* p = (char*)d_ws;
  size_t off = 0;
  auto alloc = [&](size_t bytes) {
    char* r = p + off;
    off += (bytes + 255) & ~(size_t)255;
    return r;
  };
  u16* k0t  = (u16*)alloc(3072UL * 1536 * 2);
  u16* rk0t = (u16*)alloc(3072UL * 1024 * 2);
  u16* k1t  = (u16*)alloc(3072UL * 1024 * 2);
  u16* rk1t = (u16*)alloc(3072UL * 1024 * 2);
  u16* Wdt  = (u16*)alloc(32000UL * 1024 * 2);
  u16* xin  = (u16*)alloc(2048UL * 1536 * 2);
  float* MX0 = (float*)alloc(2048UL * 3072 * 4);
  float* MX1 = (float*)alloc(64UL * 98304 * 4);    // per-t, 64 slots
  u16* H0   = (u16*)alloc(65UL * 32768 * 2);       // per-t, slots 0..64
  u16* H1   = (u16*)alloc(65UL * 32768 * 2);
  float* h0f = (float*)alloc(2UL * 32768 * 4);
  float* h1f = (float*)alloc(2UL * 32768 * 4);
  u16* seq1 = (u16*)alloc(2048UL * 1024 * 2);      // T-MAJOR: [t*32+b][1024]
  u32* bar  = (u32*)alloc(BAR_WORDS * 4);
  if (off > ws_size) return;   // ws too small -> poison output signature

  dim3 tb(32, 8);
  k_tconv4<<<13824, tb, 0, stream>>>(k0, rk0, k1, rk1, k0t, rk0t, k1t, rk1t);
  k_tconv<<<dim3(32000 / 32, 1024 / 32), tb, 0, stream>>>(Wd, Wdt, 1024, 32000);
  k_prep<<<2176, 256, 0, stream>>>(X, state, emb, xin, H0, H1, h0f, h1f, bar);

  // phase 1: MX0 = xin @ k0t + b0[0]   (grid: rows x cols = 16 x 24)
  k_gemm<<<dim3(16, 24), 256, 0, stream>>>(xin, k0t, b0, MX0, 2048, 3072, 1536);

  // phase 2: recurrence (weights in LDS) + fused logits GEMM (256 blocks)
  {
    void* args[] = {(void*)&rk0t, (void*)&k1t, (void*)&rk1t, (void*)&MX0,
                    (void*)&b0,   (void*)&b1,  (void*)&MX1,  (void*)&H0,
                    (void*)&H1,   (void*)&h0f, (void*)&h1f,  (void*)&seq1,
                    (void*)&bar,  (void*)&Wdt, (void*)&bd,   (void*)&out};
    hipLaunchCooperativeKernel((void*)k_chain, dim3(TOTAL_BLOCKS), dim3(256),
                               args, 0, stream);
  }

  // phase 3: final states (t=63 -> parity 1)
  k_states<<<128, 256, 0, stream>>>(h0f + 32768, h1f + 32768, out + 65536000UL);
}

// Round 21
// 782.374 us; speedup vs baseline: 1.0247x; 1.0247x over previous
//
#include <hip/hip_runtime.h>

// Seq2SeqDecoder: 2-layer GRU (reset_after) + logit projection, MI355X/gfx950.
// B=32 T=64 V=32000 E=512 H=1024.
// R21 = FINAL LOCK-IN: R19 chain (best verified: coop 680us, total 789us)
//       + R20's k_prep launch fusion (the only R20 piece that didn't hurt).
//       R20's all-wave polling regressed (+12us) and is reverted.
// Structure: per-t single-writer buffers + cached cross-block reads (R9),
//   flag-array sync with no RMWs (R10), weights-in-LDS chain (R19, +231us),
//   fused work-stealing logits GEMM w/ dist-2 pipeline (R13/R16), nt C-stores
//   (R11), t-major seq1. Chain floor = 66 sequential cross-XCD visibility
//   rounds (~5us latency each) -- not a throughput roofline (MfmaUtil 10%,
//   HBM 19% peak at best).
//   phase 0: k_tconv4 (fused small transposes) + k_tconv(Wd) + k_prep
//   phase 1: MX0 = xin @ k0t + b0[0]        (dist-2 pipelined bf16 MFMA GEMM)
//   phase 2: ONE cooperative kernel, 256 blocks:
//     blocks 0..191: recurrence (weights in LDS; 1-wave poll + barrier)
//     blocks 192..255 (+ finished chain blocks): work-stealing logits GEMM
//   phase 3: final states -> d_out tail

typedef __attribute__((ext_vector_type(8))) short bf16x8;
typedef __attribute__((ext_vector_type(4))) float f32x4;
typedef unsigned short u16;
typedef unsigned int u32;

#define CHAIN_BLOCKS 192
#define TOTAL_BLOCKS 256
#define NTILE 4000u              // 16 row-bands x 250 col-tiles
#define BAR_WORDS 3136           // FL0/FL1/FL2 (3x64 flags, 64B spaced) + wcnt

__device__ __forceinline__ u16 f2bf(float f) {
  unsigned int x = __float_as_uint(f);
  x += 0x7fffu + ((x >> 16) & 1u);   // RNE
  return (u16)(x >> 16);
}

// sc1 write-through stores (visible at L3 after vmcnt drain)
__device__ __forceinline__ void astoref(float* p, float v) {
  __hip_atomic_store((u32*)p, __float_as_uint(v), __ATOMIC_RELAXED,
                     __HIP_MEMORY_SCOPE_AGENT);
}
__device__ __forceinline__ void astore32(u16* p, u32 v) {
  __hip_atomic_store((u32*)p, v, __ATOMIC_RELAXED, __HIP_MEMORY_SCOPE_AGENT);
}

// ---- transpose + convert: in f32 [R][C] -> out bf16 [C][R] ----------------
__global__ void k_tconv(const float* __restrict__ in, u16* __restrict__ out,
                        int R, int C) {
  __shared__ float t[32][33];
  int tx = threadIdx.x, ty = threadIdx.y;          // 32 x 8
  int c0 = blockIdx.x * 32, r0 = blockIdx.y * 32;
#pragma unroll
  for (int i = 0; i < 4; ++i)
    t[ty + i * 8][tx] = in[(long)(r0 + ty + i * 8) * C + c0 + tx];
  __syncthreads();
#pragma unroll
  for (int i = 0; i < 4; ++i)
    out[(long)(c0 + ty + i * 8) * R + r0 + tx] = f2bf(t[tx][ty + i * 8]);
}

// ---- fused transpose of the four small weights (one launch) ---------------
__global__ void k_tconv4(const float* __restrict__ k0,
                         const float* __restrict__ rk0,
                         const float* __restrict__ k1,
                         const float* __restrict__ rk1,
                         u16* __restrict__ k0t, u16* __restrict__ rk0t,
                         u16* __restrict__ k1t, u16* __restrict__ rk1t) {
  __shared__ float t[32][33];
  int blk = blockIdx.x;
  const float* in; u16* out; int R;
  if (blk < 4608) {
    in = k0; out = k0t; R = 1536;
  } else {
    int q = (blk - 4608) / 3072;
    blk = (blk - 4608) % 3072;
    in = (q == 0) ? rk0 : (q == 1) ? k1 : rk1;
    out = (q == 0) ? rk0t : (q == 1) ? k1t : rk1t;
    R = 1024;
  }
  const int bx = blk % 96, by = blk / 96;
  const int tx = threadIdx.x, ty = threadIdx.y;    // 32 x 8
  const int c0 = bx * 32, r0 = by * 32;
#pragma unroll
  for (int i = 0; i < 4; ++i)
    t[ty + i * 8][tx] = in[(long)(r0 + ty + i * 8) * 3072 + c0 + tx];
  __syncthreads();
#pragma unroll
  for (int i = 0; i < 4; ++i)
    out[(long)(c0 + ty + i * 8) * R + r0 + tx] = f2bf(t[tx][ty + i * 8]);
}

// ---- fused embed + init (one launch) --------------------------------------
__global__ void k_prep(const int* __restrict__ X, const float* __restrict__ state,
                       const float* __restrict__ emb, u16* __restrict__ xin,
                       u16* __restrict__ H0, u16* __restrict__ H1,
                       float* __restrict__ h0f, float* __restrict__ h1f,
                       u32* __restrict__ bar) {
  const int blk = blockIdx.x;
  if (blk < 2048) {
    const int bt = blk;
    const int b = bt >> 6;
    const int tok = X[bt];
    const float* er = emb + (long)tok * 512;
    const float* cr = state + 32 * 1024 + b * 1024;  // state[-1] == state[1]
    for (int c = threadIdx.x; c < 1536; c += 256) {
      float v = (c < 512) ? er[c] : cr[c - 512];
      xin[(long)bt * 1536 + c] = f2bf(v);
    }
  } else {
    const int i = (blk - 2048) * 256 + threadIdx.x;  // 128 blocks -> 32768
    if (i < BAR_WORDS) bar[i] = 0u;
    float v0 = state[i], v1 = state[32768 + i];
    H0[i] = f2bf(v0);             // slot 0 = h0(-1)
    h0f[32768 + i] = v0;          // parity 1
    H1[i] = f2bf(v1);             // slot 0 = h1(-1)
    h1f[32768 + i] = v1;
  }
}

// ---- bf16 GEMM (MX0): dist-2 pipelined, K multiple of 64 ------------------
__global__ void k_gemm(const u16* __restrict__ A, const u16* __restrict__ Bt,
                       const float* __restrict__ bias, float* __restrict__ C,
                       int M, int N, int K) {
  __shared__ u16 As[128][40];
  __shared__ u16 Bs[128][40];
  int tid = threadIdx.x;
  int w = tid >> 6, l = tid & 63;
  int ln = l & 15, lk = l >> 4;
  int r0 = blockIdx.x * 128, c0 = blockIdx.y * 128;
  int qr = (w & 1) * 64, qc = (w >> 1) * 64;
  int sr = tid >> 1, sc = (tid & 1) * 16;
  const u16* Ap = A + (long)(r0 + sr) * K + sc;
  const u16* Bp = Bt + (long)(c0 + sr) * K + sc;
  f32x4 acc[4][4] = {};
  bf16x8 a0A = *(const bf16x8*)(Ap);
  bf16x8 a1A = *(const bf16x8*)(Ap + 8);
  bf16x8 b0A = *(const bf16x8*)(Bp);
  bf16x8 b1A = *(const bf16x8*)(Bp + 8);
  bf16x8 a0B = *(const bf16x8*)(Ap + 32);
  bf16x8 a1B = *(const bf16x8*)(Ap + 40);
  bf16x8 b0B = *(const bf16x8*)(Bp + 32);
  bf16x8 b1B = *(const bf16x8*)(Bp + 40);
  for (int kt = 0; kt < K; kt += 64) {
    __syncthreads();
    *(bf16x8*)(&As[sr][sc]) = a0A;  *(bf16x8*)(&As[sr][sc + 8]) = a1A;
    *(bf16x8*)(&Bs[sr][sc]) = b0A;  *(bf16x8*)(&Bs[sr][sc + 8]) = b1A;
    __syncthreads();
    if (kt + 64 < K) {
      a0A = *(const bf16x8*)(Ap + kt + 64);
      a1A = *(const bf16x8*)(Ap + kt + 72);
      b0A = *(const bf16x8*)(Bp + kt + 64);
      b1A = *(const bf16x8*)(Bp + kt + 72);
    }
    {
      bf16x8 af[4], bfv[4];
#pragma unroll
      for (int mt = 0; mt < 4; ++mt)
        af[mt] = *(const bf16x8*)(&As[qr + mt * 16 + ln][lk * 8]);
#pragma unroll
      for (int nt = 0; nt < 4; ++nt)
        bfv[nt] = *(const bf16x8*)(&Bs[qc + nt * 16 + ln][lk * 8]);
#pragma unroll
      for (int mt = 0; mt < 4; ++mt)
#pragma unroll
        for (int nt = 0; nt < 4; ++nt)
          acc[mt][nt] = __builtin_amdgcn_mfma_f32_16x16x32_bf16(
              af[mt], bfv[nt], acc[mt][nt], 0, 0, 0);
    }
    __syncthreads();
    *(bf16x8*)(&As[sr][sc]) = a0B;  *(bf16x8*)(&As[sr][sc + 8]) = a1B;
    *(bf16x8*)(&Bs[sr][sc]) = b0B;  *(bf16x8*)(&Bs[sr][sc + 8]) = b1B;
    __syncthreads();
    if (kt + 96 < K) {
      a0B = *(const bf16x8*)(Ap + kt + 96);
      a1B = *(const bf16x8*)(Ap + kt + 104);
      b0B = *(const bf16x8*)(Bp + kt + 96);
      b1B = *(const bf16x8*)(Bp + kt + 104);
    }
    {
      bf16x8 af[4], bfv[4];
#pragma unroll
      for (int mt = 0; mt < 4; ++mt)
        af[mt] = *(const bf16x8*)(&As[qr + mt * 16 + ln][lk * 8]);
#pragma unroll
      for (int nt = 0; nt < 4; ++nt)
        bfv[nt] = *(const bf16x8*)(&Bs[qc + nt * 16 + ln][lk * 8]);
#pragma unroll
      for (int mt = 0; mt < 4; ++mt)
#pragma unroll
        for (int nt = 0; nt < 4; ++nt)
          acc[mt][nt] = __builtin_amdgcn_mfma_f32_16x16x32_bf16(
              af[mt], bfv[nt], acc[mt][nt], 0, 0, 0);
    }
  }
#pragma unroll
  for (int mt = 0; mt < 4; ++mt)
#pragma unroll
    for (int nt = 0; nt < 4; ++nt)
#pragma unroll
      for (int r = 0; r < 4; ++r) {
        int row = r0 + qr + mt * 16 + lk * 4 + r;
        int col = c0 + qc + nt * 16 + ln;
        __builtin_nontemporal_store(acc[mt][nt][r] + bias[col],
                                    &C[(long)row * N + col]);
      }
}

// ---- cooperative: recurrence (weights in LDS) + fused logits GEMM ---------
__global__ void __launch_bounds__(256, 1)
k_chain(const u16* __restrict__ rk0t, const u16* __restrict__ k1t,
        const u16* __restrict__ rk1t, const float* __restrict__ MX0,
        const float* __restrict__ b0, const float* __restrict__ b1,
        float* __restrict__ MX1, u16* __restrict__ H0, u16* __restrict__ H1,
        float* __restrict__ h0f, float* __restrict__ h1f,
        u16* __restrict__ seq1, u32* __restrict__ bar,
        const u16* __restrict__ Wdt, const float* __restrict__ bd,
        float* __restrict__ out) {
  // 105,472 B carve: chain phase = wS(98304) + red(6144) + hbS(1024);
  // GEMM phase reuses [0,20480) as As/Bs.
  __shared__ __align__(16) char smem[105472];
  __shared__ u32 tauS;
  u16* wS = (u16*)smem;
  float (*red)[3][4][64] = (float(*)[3][4][64])(smem + 98304);
  u16 (*hbS)[16] = (u16(*)[16])(smem + 98304 + 6144);
  u16 (*As)[40] = (u16(*)[40])(smem);
  u16 (*Bs)[40] = (u16(*)[40])(smem + 10240);

  const int blk = blockIdx.x;
  const int type = blk >> 6;          // 0:L0  1:MX1  2:L1  3:helper
  const int cb = blk & 63;
  const int j0 = cb << 4;             // 16 h-cols per block
  const int tid = threadIdx.x;
  const int w = tid >> 6, l = tid & 63;
  const int ln = l & 15, lk = l >> 4;
  const int rt = w & 1, kh = w >> 1;  // row-tile (16 rows), K-half (512)

  // entry acquire: buffer_inv drops pre-launch L2 lines (per-t buffers fresh)
  if (tid == 0)
    (void)__hip_atomic_load(bar, __ATOMIC_ACQUIRE, __HIP_MEMORY_SCOPE_AGENT);
  __syncthreads();

  if (blk < CHAIN_BLOCKS) {
    // ================== R10-structure recurrence ==================
    const u16* Wt = (type == 0) ? rk0t : (type == 1) ? k1t : rk1t;
    u32* myflag = bar + type * 1024 + cb * 16;

    // ---- stage this block's 3x16x1024 weight slice into LDS (once) ----
    // layout: [gate][q=k/8][col][8] (16B units); 2-way bank aliasing = free.
    for (int idx = tid; idx < 6144; idx += 256) {
      const int g = idx >> 11;
      const int rem = idx & 2047;
      const int c = rem >> 7;             // col 0..15
      const int q = rem & 127;            // k-chunk 0..127
      *(bf16x8*)(wS + g * 16384 + (((q << 4) + c) << 3)) =
          *(const bf16x8*)(Wt + ((long)g << 20) + (long)(j0 + c) * 1024 +
                           (q << 3));
    }
    __syncthreads();
    const u16* wls = wS + ((((kh << 6) + lk) << 4) + ln) * 8;

    for (int s = 0; s < 66; ++s) {
      const int tt = (type == 0) ? s : (type == 1) ? s - 1 : s - 2;
      const bool active = (tt >= 0) && (tt < 64);

      // MX0 prefetch (static data, issued BEFORE the poll)
      float pf[4][3];
      if (type == 0 && kh == 0 && active) {
        const int j = j0 + ln;
#pragma unroll
        for (int r = 0; r < 4; ++r) {
          const float* mx = MX0 + (((long)(rt * 16 + lk * 4 + r)) * 64 + tt) * 3072;
          pf[r][0] = mx[j]; pf[r][1] = mx[1024 + j]; pf[r][2] = mx[2048 + j];
        }
      }

      // dependency poll: one wave scans flags; barrier releases the block
      if (tid < 64) {
        const u32 tgt = (u32)s;
        if (type != 2) {
          const u32* f = bar + tid * 16;                       // FL0
          while (true) {
            u32 v = __hip_atomic_load(f, __ATOMIC_RELAXED,
                                      __HIP_MEMORY_SCOPE_AGENT);
            if (__all(v >= tgt)) break;
            __builtin_amdgcn_s_sleep(1);
          }
        } else {
          const u32* fa = bar + 1024 + tid * 16;               // FL1
          const u32* fb = bar + 2048 + tid * 16;               // FL2
          while (true) {
            u32 va = __hip_atomic_load(fa, __ATOMIC_RELAXED,
                                       __HIP_MEMORY_SCOPE_AGENT);
            u32 vb = __hip_atomic_load(fb, __ATOMIC_RELAXED,
                                       __HIP_MEMORY_SCOPE_AGENT);
            if (__all(va >= tgt && vb >= tgt)) break;
            __builtin_amdgcn_s_sleep(1);
          }
        }
      }
      __syncthreads();

      f32x4 acc[3] = {};
      if (active) {
        if (type == 2 && kh == 0) {
          const int j = j0 + ln;
#pragma unroll
          for (int r = 0; r < 4; ++r) {
            const float* mx = MX1 + (long)tt * 98304 +
                              (long)(rt * 16 + lk * 4 + r) * 3072;
            pf[r][0] = mx[j]; pf[r][1] = mx[1024 + j]; pf[r][2] = mx[2048 + j];
          }
        }
        const u16* Ab = (type == 2) ? H1 + (long)tt * 32768
                                    : H0 + (long)s * 32768;
        const u16* hp = Ab + (rt * 16 + ln) * 1024 + kh * 512 + lk * 8;
        bf16x8 afr[16];
#pragma unroll
        for (int ks = 0; ks < 16; ++ks)
          afr[ks] = *(const bf16x8*)(hp + ks * 32);
#pragma unroll
        for (int ks = 0; ks < 16; ++ks) {
          bf16x8 bv0 = *(const bf16x8*)(wls + ks * 512);
          bf16x8 bv1 = *(const bf16x8*)(wls + 16384 + ks * 512);
          bf16x8 bv2 = *(const bf16x8*)(wls + 32768 + ks * 512);
          acc[0] = __builtin_amdgcn_mfma_f32_16x16x32_bf16(afr[ks], bv0, acc[0], 0, 0, 0);
          acc[1] = __builtin_amdgcn_mfma_f32_16x16x32_bf16(afr[ks], bv1, acc[1], 0, 0, 0);
          acc[2] = __builtin_amdgcn_mfma_f32_16x16x32_bf16(afr[ks], bv2, acc[2], 0, 0, 0);
        }
        if (kh == 1) {
#pragma unroll
          for (int g = 0; g < 3; ++g)
#pragma unroll
            for (int r = 0; r < 4; ++r)
              red[rt][g][r][l] = acc[g][r];
        }
      }
      __syncthreads();
      if (active && kh == 0) {
#pragma unroll
        for (int r = 0; r < 4; ++r) {
          const int row = rt * 16 + lk * 4 + r;    // batch b
          const int j = j0 + ln;
          float mz = acc[0][r] + red[rt][0][r][l];
          float mr = acc[1][r] + red[rt][1][r][l];
          float mh = acc[2][r] + red[rt][2][r][l];
          if (type == 1) {
            float* o = MX1 + (long)tt * 98304 + (long)row * 3072;
            astoref(o + j,        mz + b1[j]);
            astoref(o + 1024 + j, mr + b1[1024 + j]);
            astoref(o + 2048 + j, mh + b1[2048 + j]);
          } else {
            const float* bias = (type == 0) ? b0 + 3072 : b1 + 3072;  // b[1]
            float miz = mz + bias[j];
            float mir = mr + bias[1024 + j];
            float mih = mh + bias[2048 + j];
            float z  = 1.f / (1.f + expf(-(pf[r][0] + miz)));
            float rg = 1.f / (1.f + expf(-(pf[r][1] + mir)));
            float hh = tanhf(pf[r][2] + rg * mih);
            float* hf = (type == 0) ? h0f : h1f;
            float hold = hf[(long)((tt + 1) & 1) * 32768 + row * 1024 + j];
            float hn = z * hold + (1.f - z) * hh;
            hf[(long)(tt & 1) * 32768 + row * 1024 + j] = hn;
            hbS[row][ln] = f2bf(hn);
          }
        }
      }
      if (type != 1) {
        __syncthreads();
        if (active) {
          const int row = tid >> 3, cp = tid & 7;
          const u32 v = ((const u32*)&hbS[row][0])[cp];
          const int j = j0 + cp * 2;
          if (type == 0) {
            astore32(&H0[(long)(tt + 1) * 32768 + row * 1024 + j], v);
          } else {
            astore32(&H1[(long)(tt + 1) * 32768 + row * 1024 + j], v);
            // seq1 T-MAJOR (row = t*32 + b), sc1 so helper blocks see it
            astore32(&seq1[((long)tt * 32 + row) * 1024 + j], v);
          }
        }
      }
      asm volatile("s_waitcnt vmcnt(0)" ::: "memory");
      __syncthreads();
      if (tid == 0)
        __hip_atomic_store(myflag, (u32)(s + 1), __ATOMIC_RELAXED,
                           __HIP_MEMORY_SCOPE_AGENT);
    }
  }

  // ================== fused logits GEMM (all blocks) ==================
  // out[b*64+t][v] = seq1_tmajor[t*32+b][:] @ Wdt[v][:] + bd[v]
  u32* wcnt = bar + 3072;
  const int qr = (w & 1) * 64, qc = (w >> 1) * 64;
  const int sr = tid >> 1, sc = (tid & 1) * 16;
  u32 seen = 0;
  for (;;) {
    if (tid == 0) tauS = atomicAdd(wcnt, 1u);
    __syncthreads();
    const u32 tau = tauS;
    __syncthreads();
    if (tau >= NTILE) break;
    const u32 rr = tau / 250u, cc = tau % 250u;
    u32 need = 4u * rr + 6u; if (need > 66u) need = 66u;
    if (seen < need) {
      if (tid < 64) {
        const u32* f = bar + 2048 + tid * 16;                  // FL2
        while (true) {
          u32 v = __hip_atomic_load(f, __ATOMIC_RELAXED,
                                    __HIP_MEMORY_SCOPE_AGENT);
          if (__all(v >= need)) break;
          __builtin_amdgcn_s_sleep(32);
        }
      }
      __syncthreads();
      seen = need;
    }
    const int r0g = (int)rr * 128, c0g = (int)cc * 128;
    const u16* Ap = seq1 + (long)(r0g + sr) * 1024 + sc;
    const u16* Bp = Wdt + (long)(c0g + sr) * 1024 + sc;
    f32x4 accg[4][4] = {};
    bf16x8 a0A = *(const bf16x8*)(Ap);
    bf16x8 a1A = *(const bf16x8*)(Ap + 8);
    bf16x8 b0A = *(const bf16x8*)(Bp);
    bf16x8 b1A = *(const bf16x8*)(Bp + 8);
    bf16x8 a0B = *(const bf16x8*)(Ap + 32);
    bf16x8 a1B = *(const bf16x8*)(Ap + 40);
    bf16x8 b0B = *(const bf16x8*)(Bp + 32);
    bf16x8 b1B = *(const bf16x8*)(Bp + 40);
    for (int kt = 0; kt < 1024; kt += 64) {
      __syncthreads();
      *(bf16x8*)(&As[sr][sc]) = a0A;  *(bf16x8*)(&As[sr][sc + 8]) = a1A;
      *(bf16x8*)(&Bs[sr][sc]) = b0A;  *(bf16x8*)(&Bs[sr][sc + 8]) = b1A;
      __syncthreads();
      if (kt + 64 < 1024) {
        a0A = *(const bf16x8*)(Ap + kt + 64);
        a1A = *(const bf16x8*)(Ap + kt + 72);
        b0A = *(const bf16x8*)(Bp + kt + 64);
        b1A = *(const bf16x8*)(Bp + kt + 72);
      }
      {
        bf16x8 af[4], bfv[4];
#pragma unroll
        for (int mt = 0; mt < 4; ++mt)
          af[mt] = *(const bf16x8*)(&As[qr + mt * 16 + ln][lk * 8]);
#pragma unroll
        for (int nt = 0; nt < 4; ++nt)
          bfv[nt] = *(const bf16x8*)(&Bs[qc + nt * 16 + ln][lk * 8]);
#pragma unroll
        for (int mt = 0; mt < 4; ++mt)
#pragma unroll
          for (int nt = 0; nt < 4; ++nt)
            accg[mt][nt] = __builtin_amdgcn_mfma_f32_16x16x32_bf16(
                af[mt], bfv[nt], accg[mt][nt], 0, 0, 0);
      }
      __syncthreads();
      *(bf16x8*)(&As[sr][sc]) = a0B;  *(bf16x8*)(&As[sr][sc + 8]) = a1B;
      *(bf16x8*)(&Bs[sr][sc]) = b0B;  *(bf16x8*)(&Bs[sr][sc + 8]) = b1B;
      __syncthreads();
      if (kt + 96 < 1024) {
        a0B = *(const bf16x8*)(Ap + kt + 96);
        a1B = *(const bf16x8*)(Ap + kt + 104);
        b0B = *(const bf16x8*)(Bp + kt + 96);
        b1B = *(const bf16x8*)(Bp + kt + 104);
      }
      {
        bf16x8 af[4], bfv[4];
#pragma unroll
        for (int mt = 0; mt < 4; ++mt)
          af[mt] = *(const bf16x8*)(&As[qr + mt * 16 + ln][lk * 8]);
#pragma unroll
        for (int nt = 0; nt < 4; ++nt)
          bfv[nt] = *(const bf16x8*)(&Bs[qc + nt * 16 + ln][lk * 8]);
#pragma unroll
        for (int mt = 0; mt < 4; ++mt)
#pragma unroll
          for (int nt = 0; nt < 4; ++nt)
            accg[mt][nt] = __builtin_amdgcn_mfma_f32_16x16x32_bf16(
                af[mt], bfv[nt], accg[mt][nt], 0, 0, 0);
      }
    }
    __syncthreads();   // LDS safe before next tile's writes
#pragma unroll
    for (int mt = 0; mt < 4; ++mt)
#pragma unroll
      for (int nt = 0; nt < 4; ++nt)
#pragma unroll
        for (int r = 0; r < 4; ++r) {
          const int m = r0g + qr + mt * 16 + lk * 4 + r;       // t*32+b
          const int orow = (m & 31) * 64 + (m >> 5);           // b*64+t
          const int col = c0g + qc + nt * 16 + ln;
          __builtin_nontemporal_store(accg[mt][nt][r] + bd[col],
                                      &out[(long)orow * 32000 + col]);
        }
  }
}

__global__ void k_states(const float* __restrict__ h0, const float* __restrict__ h1,
                         float* __restrict__ out) {
  int i = blockIdx.x * 256 + threadIdx.x;        // grid 128
  out[i] = h0[i];
  out[32768 + i] = h1[i];
}

extern "C" void kernel_launch(void* const* d_in, const int* in_sizes, int n_in,
                              void* d_out, int out_size, void* d_ws, size_t ws_size,
                              hipStream_t stream) {
  const int*   X     = (const int*)  d_in[0];
  const float* state = (const float*)d_in[1];
  const float* emb   = (const float*)d_in[2];
  const float* k0    = (const float*)d_in[3];
  const float* rk0   = (const float*)d_in[4];
  const float* b0    = (const float*)d_in[5];
  const float* k1    = (const float*)d_in[6];
  const float* rk1   = (const float*)d_in[7];
  const float* b1    = (const float*)d_in[8];
  const float* Wd    = (const float*)d_in[9];
  const float* bd    = (const float*)d_in[10];
  float* out = (float*)d_out;

  char* p = (char*)d_ws;
  size_t off = 0;
  auto alloc = [&](size_t bytes) {
    char* r = p + off;
    off += (bytes + 255) & ~(size_t)255;
    return r;
  };
  u16* k0t  = (u16*)alloc(3072UL * 1536 * 2);
  u16* rk0t = (u16*)alloc(3072UL * 1024 * 2);
  u16* k1t  = (u16*)alloc(3072UL * 1024 * 2);
  u16* rk1t = (u16*)alloc(3072UL * 1024 * 2);
  u16* Wdt  = (u16*)alloc(32000UL * 1024 * 2);
  u16* xin  = (u16*)alloc(2048UL * 1536 * 2);
  float* MX0 = (float*)alloc(2048UL * 3072 * 4);
  float* MX1 = (float*)alloc(64UL * 98304 * 4);    // per-t, 64 slots
  u16* H0   = (u16*)alloc(65UL * 32768 * 2);       // per-t, slots 0..64
  u16* H1   = (u16*)alloc(65UL * 32768 * 2);
  float* h0f = (float*)alloc(2UL * 32768 * 4);
  float* h1f = (float*)alloc(2UL * 32768 * 4);
  u16* seq1 = (u16*)alloc(2048UL * 1024 * 2);      // T-MAJOR: [t*32+b][1024]
  u32* bar  = (u32*)alloc(BAR_WORDS * 4);
  if (off > ws_size) return;   // ws too small -> poison output signature

  dim3 tb(32, 8);
  k_tconv4<<<13824, tb, 0, stream>>>(k0, rk0, k1, rk1, k0t, rk0t, k1t, rk1t);
  k_tconv<<<dim3(32000 / 32, 1024 / 32), tb, 0, stream>>>(Wd, Wdt, 1024, 32000);
  k_prep<<<2176, 256, 0, stream>>>(X, state, emb, xin, H0, H1, h0f, h1f, bar);

  // phase 1: MX0 = xin @ k0t + b0[0]   (grid: rows x cols = 16 x 24)
  k_gemm<<<dim3(16, 24), 256, 0, stream>>>(xin, k0t, b0, MX0, 2048, 3072, 1536);

  // phase 2: recurrence (weights in LDS) + fused logits GEMM (256 blocks)
  {
    void* args[] = {(void*)&rk0t, (void*)&k1t, (void*)&rk1t, (void*)&MX0,
                    (void*)&b0,   (void*)&b1,  (void*)&MX1,  (void*)&H0,
                    (void*)&H1,   (void*)&h0f, (void*)&h1f,  (void*)&seq1,
                    (void*)&bar,  (void*)&Wdt, (void*)&bd,   (void*)&out};
    hipLaunchCooperativeKernel((void*)k_chain, dim3(TOTAL_BLOCKS), dim3(256),
                               args, 0, stream);
  }

  // phase 3: final states (t=63 -> parity 1)
  k_states<<<128, 256, 0, stream>>>(h0f + 32768, h1f + 32768, out + 65536000UL);
}